// Round 1
// baseline (55.810 us; speedup 1.0000x reference)
//
#include <hip/hip_runtime.h>
#include <float.h>

#define NPTS   4096
#define NB     8
#define BLOCK  256
#define QB     64              // queries per block
#define KQUART 4               // db quarters per block (== BLOCK/QB waves)
#define NCHUNK (NPTS / QB)     // 64 query chunks

// grid: (NCHUNK, 2, NB), block: 256
// dir 0: query = preds, db = gts   (loss_1)
// dir 1: query = gts,   db = preds (loss_2)
__global__ void __launch_bounds__(BLOCK) chamfer_partial(
    const float* __restrict__ preds,
    const float* __restrict__ gts,
    float* __restrict__ ws)
{
    __shared__ float pts[NPTS * 3];       // 48 KB
    __shared__ float comb[BLOCK];

    const int tid   = threadIdx.x;
    const int chunk = blockIdx.x;
    const int dir   = blockIdx.y;
    const int b     = blockIdx.z;

    const float* query = (dir == 0) ? preds : gts;
    const float* db    = (dir == 0) ? gts   : preds;
    query += (size_t)b * NPTS * 3;
    db    += (size_t)b * NPTS * 3;

    // stage full db point set into LDS as float4s (3072 float4)
    const float4* db4  = reinterpret_cast<const float4*>(db);
    float4*       lds4w = reinterpret_cast<float4*>(pts);
    #pragma unroll
    for (int i = tid; i < NPTS * 3 / 4; i += BLOCK) lds4w[i] = db4[i];
    __syncthreads();

    const int lane = tid & (QB - 1);      // query within chunk (0..63)
    const int k    = tid / QB;            // db quarter (0..3)

    const int qg = chunk * QB + lane;
    const float qx = query[qg * 3 + 0];
    const float qy = query[qg * 3 + 1];
    const float qz = query[qg * 3 + 2];

    const float4* lds4 = reinterpret_cast<const float4*>(pts);
    float mn0 = FLT_MAX, mn1 = FLT_MAX, mn2 = FLT_MAX, mn3 = FLT_MAX;

    const int u0 = k * (NPTS / 4 / KQUART);       // 256 u-groups per quarter
    const int u1 = u0 + (NPTS / 4 / KQUART);
    #pragma unroll 4
    for (int u = u0; u < u1; ++u) {
        const float4 a = lds4[3 * u + 0];
        const float4 bb = lds4[3 * u + 1];
        const float4 c = lds4[3 * u + 2];
        float dx, dy, dz;
        dx = qx - a.x;  dy = qy - a.y;  dz = qz - a.z;
        mn0 = fminf(mn0, dx * dx + dy * dy + dz * dz);
        dx = qx - a.w;  dy = qy - bb.x; dz = qz - bb.y;
        mn1 = fminf(mn1, dx * dx + dy * dy + dz * dz);
        dx = qx - bb.z; dy = qy - bb.w; dz = qz - c.x;
        mn2 = fminf(mn2, dx * dx + dy * dy + dz * dz);
        dx = qx - c.y;  dy = qy - c.z;  dz = qz - c.w;
        mn3 = fminf(mn3, dx * dx + dy * dy + dz * dz);
    }
    float mn = fminf(fminf(mn0, mn1), fminf(mn2, mn3));

    comb[tid] = mn;
    __syncthreads();

    if (tid < QB) {
        float m = fminf(fminf(comb[tid], comb[tid + 64]),
                        fminf(comb[tid + 128], comb[tid + 192]));
        // sum the 64 per-query mins of this chunk across the wave
        #pragma unroll
        for (int off = 32; off > 0; off >>= 1) m += __shfl_down(m, off, 64);
        if (tid == 0)
            ws[((b * 2 + dir) << 6) + chunk] = m;   // one partial per block
    }
}

// single block; threads 0..7 each sum their batch's 128 partials (fixed order)
__global__ void chamfer_final(const float* __restrict__ ws, float* __restrict__ out)
{
    const int b = threadIdx.x;
    if (b < NB) {
        float s = 0.0f;
        #pragma unroll 8
        for (int i = 0; i < 2 * NCHUNK; ++i) s += ws[b * 2 * NCHUNK + i];
        out[b] = s;
    }
}

extern "C" void kernel_launch(void* const* d_in, const int* in_sizes, int n_in,
                              void* d_out, int out_size, void* d_ws, size_t ws_size,
                              hipStream_t stream)
{
    const float* preds = (const float*)d_in[0];
    const float* gts   = (const float*)d_in[1];
    float* out = (float*)d_out;
    float* ws  = (float*)d_ws;

    dim3 grid(NCHUNK, 2, NB);
    chamfer_partial<<<grid, BLOCK, 0, stream>>>(preds, gts, ws);
    chamfer_final<<<1, 64, 0, stream>>>(ws, out);
}

// Round 2
// 38.921 us; speedup vs baseline: 1.4339x; 1.4339x over previous
//
#include <hip/hip_runtime.h>
#include <float.h>

#define NPTS  4096
#define NB    8
#define BLOCK 256
#define QPT   16          // queries per thread (16*256 = 4096 = all queries per (b,dir))

// ---------------- main: per-slice partial mins ----------------
// grid (S, 16), block 256.  bdir = b*2 + dir
// dir 0: query = preds, db = gts   (loss_1)
// dir 1: query = gts,   db = preds (loss_2)
__global__ void __launch_bounds__(BLOCK) chamfer_main(
    const float* __restrict__ preds,
    const float* __restrict__ gts,
    float* __restrict__ part, int S)
{
    __shared__ float4 pt[512];            // max pts_slice (S>=8) ; 8 KB

    const int slice = blockIdx.x;
    const int bdir  = blockIdx.y;
    const int b = bdir >> 1, dir = bdir & 1;
    const int tid = threadIdx.x;
    const int pts_slice = NPTS / S;

    const float* query = ((dir == 0) ? preds : gts) + (size_t)b * NPTS * 3;
    const float* db    = ((dir == 0) ? gts : preds) + (size_t)b * NPTS * 3;

    // stage db slice into LDS as (x,y,z,||p||^2)
    for (int i = tid; i < pts_slice; i += BLOCK) {
        const float* p = db + (size_t)(slice * pts_slice + i) * 3;
        float x = p[0], y = p[1], z = p[2];
        pt[i] = make_float4(x, y, z, x * x + y * y + z * z);
    }

    // query constants: -2*q  (h_q added in the combine kernel)
    float m2x[QPT], m2y[QPT], m2z[QPT], mn[QPT];
    #pragma unroll
    for (int j = 0; j < QPT; ++j) {
        const float* q = query + (size_t)(j * BLOCK + tid) * 3;
        m2x[j] = -2.0f * q[0];
        m2y[j] = -2.0f * q[1];
        m2z[j] = -2.0f * q[2];
        mn[j] = FLT_MAX;
    }
    __syncthreads();

    // min over slice: t = h_p - 2 q.p   (3 fma); two points per iter -> v_min3
    for (int p = 0; p < pts_slice; p += 2) {
        const float4 a = pt[p];
        const float4 c = pt[p + 1];
        #pragma unroll
        for (int j = 0; j < QPT; ++j) {
            float ta = fmaf(a.z, m2z[j], fmaf(a.y, m2y[j], fmaf(a.x, m2x[j], a.w)));
            float tb = fmaf(c.z, m2z[j], fmaf(c.y, m2y[j], fmaf(c.x, m2x[j], c.w)));
            mn[j] = fminf(fminf(mn[j], ta), tb);
        }
    }

    // write per-query partial mins for this slice (coalesced)
    float* pp = part + (size_t)(bdir * S + slice) * NPTS;
    #pragma unroll
    for (int j = 0; j < QPT; ++j) pp[j * BLOCK + tid] = mn[j];
}

// ---------------- combine 1: min over slices, add h_q, block-sum ----------------
// grid (16 qgroups, 16 bdir), block 256 -> ws2[bdir*16 + qg]
__global__ void __launch_bounds__(BLOCK) chamfer_comb1(
    const float* __restrict__ preds,
    const float* __restrict__ gts,
    const float* __restrict__ part,
    float* __restrict__ ws2, int S)
{
    const int qg = blockIdx.x, bdir = blockIdx.y;
    const int b = bdir >> 1, dir = bdir & 1;
    const int tid = threadIdx.x;
    const int q = qg * BLOCK + tid;

    const float* query = ((dir == 0) ? preds : gts) + (size_t)b * NPTS * 3;

    float m = FLT_MAX;
    const float* pp = part + (size_t)bdir * S * NPTS + q;
    for (int s = 0; s < S; ++s) m = fminf(m, pp[(size_t)s * NPTS]);

    const float x = query[q * 3 + 0], y = query[q * 3 + 1], z = query[q * 3 + 2];
    float v = m + (x * x + y * y + z * z);

    __shared__ float red[BLOCK];
    red[tid] = v;
    __syncthreads();
    #pragma unroll
    for (int off = BLOCK / 2; off >= 1; off >>= 1) {
        if (tid < off) red[tid] += red[tid + off];
        __syncthreads();
    }
    if (tid == 0) ws2[bdir * 16 + qg] = red[0];
}

// ---------------- combine 2: out[b] = sum of its 32 group sums ----------------
__global__ void chamfer_comb2(const float* __restrict__ ws2, float* __restrict__ out)
{
    const int b = threadIdx.x;
    if (b < NB) {
        float s = 0.0f;
        #pragma unroll
        for (int i = 0; i < 32; ++i) s += ws2[b * 32 + i];
        out[b] = s;
    }
}

extern "C" void kernel_launch(void* const* d_in, const int* in_sizes, int n_in,
                              void* d_out, int out_size, void* d_ws, size_t ws_size,
                              hipStream_t stream)
{
    const float* preds = (const float*)d_in[0];
    const float* gts   = (const float*)d_in[1];
    float* out = (float*)d_out;

    // pick largest slice count whose partial buffer fits in ws
    int S = 32;
    while (S > 8 && (size_t)(2 * NB) * S * NPTS * 4 + 1024 > ws_size) S >>= 1;

    float* part = (float*)d_ws;
    float* ws2  = part + (size_t)(2 * NB) * S * NPTS;   // 256 floats

    dim3 gmain(S, 2 * NB);
    chamfer_main<<<gmain, BLOCK, 0, stream>>>(preds, gts, part, S);

    dim3 gcomb(NPTS / BLOCK, 2 * NB);
    chamfer_comb1<<<gcomb, BLOCK, 0, stream>>>(preds, gts, part, ws2, S);

    chamfer_comb2<<<1, 64, 0, stream>>>(ws2, out);
}